// Round 1
// baseline (238.864 us; speedup 1.0000x reference)
//
#include <hip/hip_runtime.h>

#define EPS 1e-5f
#define TILE 8

// ---------------------------------------------------------------------------
// k_encode: per block = (side, b, 8 consecutive n-rows).
// Computes: h1 = relu(LN(app @ wa1 + ba1))            (K=1024 GEMM, fused LN)
//           g  = relu(LN(geo @ wg1 + bg1)) @ wg2 + bg2
//           emb = LN(h1 @ wa2 + ba2 + g)
//           proj = emb @ wc1_half   -> a (tracks side) or c (detections side)
// Attention branch of the reference is dead code (attn_out unused) — skipped.
// ---------------------------------------------------------------------------
__global__ __launch_bounds__(256) void k_encode(
    const float* __restrict__ tracks, const float* __restrict__ dets,
    const float* __restrict__ wa1, const float* __restrict__ ba1,
    const float* __restrict__ gla, const float* __restrict__ bla,
    const float* __restrict__ wa2, const float* __restrict__ ba2,
    const float* __restrict__ wg1, const float* __restrict__ bg1,
    const float* __restrict__ glg, const float* __restrict__ blg,
    const float* __restrict__ wg2, const float* __restrict__ bg2,
    const float* __restrict__ gf,  const float* __restrict__ bf,
    const float* __restrict__ wc1,
    float* __restrict__ aout, float* __restrict__ cout)
{
    __shared__ float xs[1024 * TILE];      // 32 KB; overlaid in phase 2
    __shared__ float red[4][TILE][2];      // per-wave partial (sum, sumsq)
    __shared__ float geo_s[TILE][4];

    // phase-2 overlay of the (then-dead) xs slab:
    float* h1s   = xs;               // [TILE][256]   8 KB
    float* grelu = xs + TILE * 256;  // [TILE][128]   4 KB
    float* emb   = xs + TILE * 384;  // [TILE][256]   8 KB
    float* psum  = xs + TILE * 640;  // [2][TILE][128] 8 KB  (ends at 7168 < 8192)

    const int blk  = blockIdx.x;       // 256 blocks: side(2) * b(4) * tiles(32)
    const int side = blk >> 7;
    const int rem  = blk & 127;
    const int b    = rem >> 5;
    const int n0   = (rem & 31) * TILE;
    const float* x  = side ? dets : tracks;
    const float* xb = x + (size_t)b * (1028 * 256);

    const int tid  = threadIdx.x;
    const int wave = tid >> 6, lane = tid & 63;
    const int c    = tid;          // output channel, 0..255
    const int j    = tid & 127;    // 128-wide index

    // ---- phase 1: stage app slab (1024 x 8), big GEMM ----
    for (int idx = tid; idx < 1024 * TILE; idx += 256) {
        int f = idx >> 3, i = idx & 7;
        xs[idx] = xb[f * 256 + n0 + i];
    }
    if (tid < TILE * 4) {
        geo_s[tid >> 2][tid & 3] = xb[(1024 + (tid & 3)) * 256 + n0 + (tid >> 2)];
    }
    __syncthreads();

    float acc[TILE];
#pragma unroll
    for (int i = 0; i < TILE; ++i) acc[i] = 0.f;
#pragma unroll 4
    for (int f = 0; f < 1024; ++f) {
        float w = wa1[f * 256 + c];              // coalesced, L2-resident
#pragma unroll
        for (int i = 0; i < TILE; ++i)
            acc[i] = fmaf(xs[f * TILE + i], w, acc[i]);  // LDS broadcast
    }
    {
        float bav = ba1[c];
#pragma unroll
        for (int i = 0; i < TILE; ++i) acc[i] += bav;
    }

    // LN over c (256) per row, then relu, write h1s (overlays xs)
#pragma unroll
    for (int i = 0; i < TILE; ++i) {
        float s = acc[i], s2 = acc[i] * acc[i];
#pragma unroll
        for (int off = 32; off >= 1; off >>= 1) {
            s  += __shfl_xor(s,  off, 64);
            s2 += __shfl_xor(s2, off, 64);
        }
        if (lane == 0) { red[wave][i][0] = s; red[wave][i][1] = s2; }
    }
    __syncthreads();   // red ready; all xs reads done -> overlay is safe
    {
        float gv = gla[c], bv = bla[c];
#pragma unroll
        for (int i = 0; i < TILE; ++i) {
            float s  = red[0][i][0] + red[1][i][0] + red[2][i][0] + red[3][i][0];
            float s2 = red[0][i][1] + red[1][i][1] + red[2][i][1] + red[3][i][1];
            float m   = s * (1.f / 256.f);
            float var = s2 * (1.f / 256.f) - m * m;
            float v = (acc[i] - m) * rsqrtf(var + EPS) * gv + bv;
            h1s[i * 256 + c] = fmaxf(v, 0.f);
        }
    }
    __syncthreads();   // h1s visible; red reads done before reuse below

    // ---- phase 2a: geo MLP: gh = geo @ wg1 + bg1, LN(128), relu ----
    float ghv[TILE];
    if (tid < 128) {
#pragma unroll
        for (int i = 0; i < TILE; ++i) {
            float s = bg1[j];
#pragma unroll
            for (int f = 0; f < 4; ++f)
                s = fmaf(geo_s[i][f], wg1[f * 128 + j], s);
            ghv[i] = s;
        }
#pragma unroll
        for (int i = 0; i < TILE; ++i) {
            float s = ghv[i], s2 = ghv[i] * ghv[i];
#pragma unroll
            for (int off = 32; off >= 1; off >>= 1) {
                s  += __shfl_xor(s,  off, 64);
                s2 += __shfl_xor(s2, off, 64);
            }
            if (lane == 0) { red[wave][i][0] = s; red[wave][i][1] = s2; }
        }
    }
    __syncthreads();
    if (tid < 128) {
        float gvj = glg[j], bvj = blg[j];
#pragma unroll
        for (int i = 0; i < TILE; ++i) {
            float s  = red[0][i][0] + red[1][i][0];
            float s2 = red[0][i][1] + red[1][i][1];
            float m   = s * (1.f / 128.f);
            float var = s2 * (1.f / 128.f) - m * m;
            float v = (ghv[i] - m) * rsqrtf(var + EPS) * gvj + bvj;
            grelu[i * 128 + j] = fmaxf(v, 0.f);
        }
    }
    __syncthreads();

    // ---- phase 2b: h2 = h1s@wa2 + grelu@wg2 + ba2 + bg2, LN(256) -> emb ----
    float acc2[TILE];
    {
        float bb = ba2[c] + bg2[c];
#pragma unroll
        for (int i = 0; i < TILE; ++i) acc2[i] = bb;
    }
#pragma unroll 4
    for (int k = 0; k < 256; ++k) {
        float w = wa2[k * 256 + c];
#pragma unroll
        for (int i = 0; i < TILE; ++i)
            acc2[i] = fmaf(h1s[i * 256 + k], w, acc2[i]);
    }
#pragma unroll 4
    for (int k = 0; k < 128; ++k) {
        float w = wg2[k * 256 + c];
#pragma unroll
        for (int i = 0; i < TILE; ++i)
            acc2[i] = fmaf(grelu[i * 128 + k], w, acc2[i]);
    }
#pragma unroll
    for (int i = 0; i < TILE; ++i) {
        float s = acc2[i], s2 = acc2[i] * acc2[i];
#pragma unroll
        for (int off = 32; off >= 1; off >>= 1) {
            s  += __shfl_xor(s,  off, 64);
            s2 += __shfl_xor(s2, off, 64);
        }
        if (lane == 0) { red[wave][i][0] = s; red[wave][i][1] = s2; }
    }
    __syncthreads();
    {
        float gfc = gf[c], bfc = bf[c];
#pragma unroll
        for (int i = 0; i < TILE; ++i) {
            float s  = red[0][i][0] + red[1][i][0] + red[2][i][0] + red[3][i][0];
            float s2 = red[0][i][1] + red[1][i][1] + red[2][i][1] + red[3][i][1];
            float m   = s * (1.f / 256.f);
            float var = s2 * (1.f / 256.f) - m * m;
            emb[i * 256 + c] = (acc2[i] - m) * rsqrtf(var + EPS) * gfc + bfc;
        }
    }
    __syncthreads();

    // ---- phase 3: projection with this side's wc1 half -> a or c rows ----
    const float* wc1h = wc1 + (size_t)side * (256 * 128);
    const int half = tid >> 7;
    float p[TILE];
#pragma unroll
    for (int i = 0; i < TILE; ++i) p[i] = 0.f;
#pragma unroll 4
    for (int k = half * 128; k < half * 128 + 128; ++k) {
        float w = wc1h[k * 128 + j];
#pragma unroll
        for (int i = 0; i < TILE; ++i)
            p[i] = fmaf(emb[i * 256 + k], w, p[i]);
    }
#pragma unroll
    for (int i = 0; i < TILE; ++i) psum[(half * TILE + i) * 128 + j] = p[i];
    __syncthreads();

    float* outp = (side ? cout : aout) + ((size_t)b * 256 + n0) * 128;
    for (int idx = tid; idx < TILE * 128; idx += 256) {
        int i = idx >> 7, jo = idx & 127;
        outp[i * 128 + jo] = psum[i * 128 + jo] + psum[(TILE + i) * 128 + jo];
    }
}

// ---------------------------------------------------------------------------
// k_pairwise: logits[b,n,m] = sum_j relu(a[b,n,j] + c[b,m,j] + bc1[j])*wc2[j]
//             + bc2.  16x16 (n,m) tile per block, one output per thread.
// ---------------------------------------------------------------------------
__global__ __launch_bounds__(256) void k_pairwise(
    const float* __restrict__ a, const float* __restrict__ c,
    const float* __restrict__ bc1, const float* __restrict__ wc2,
    const float* __restrict__ bc2, float* __restrict__ out)
{
    const int S = 130;                       // padded stride: conflict-free
    __shared__ float a_s[16 * S];
    __shared__ float c_s[16 * S];
    __shared__ float w_s[128];

    const int blk = blockIdx.x;              // 4 * 16 * 16 = 1024 blocks
    const int b   = blk >> 8;
    const int rem = blk & 255;
    const int n0  = (rem >> 4) << 4;
    const int m0  = (rem & 15) << 4;

    const int tid = threadIdx.x;
    for (int idx = tid; idx < 16 * 128; idx += 256) {
        int r = idx >> 7, jj = idx & 127;
        a_s[r * S + jj] = a[((size_t)b * 256 + n0 + r) * 128 + jj] + bc1[jj];
        c_s[r * S + jj] = c[((size_t)b * 256 + m0 + r) * 128 + jj];
    }
    if (tid < 128) w_s[tid] = wc2[tid];
    __syncthreads();

    const int ni = tid >> 4, mi = tid & 15;
    const float* ap = a_s + ni * S;
    const float* cp = c_s + mi * S;
    float acc = bc2[0];
#pragma unroll 8
    for (int jj = 0; jj < 128; ++jj) {
        acc = fmaf(fmaxf(ap[jj] + cp[jj], 0.f), w_s[jj], acc);
    }
    out[((size_t)b * 256 + n0 + ni) * 256 + m0 + mi] = acc;
}

extern "C" void kernel_launch(void* const* d_in, const int* in_sizes, int n_in,
                              void* d_out, int out_size, void* d_ws, size_t ws_size,
                              hipStream_t stream)
{
    const float* tracks = (const float*)d_in[0];
    const float* dets   = (const float*)d_in[1];
    const float* wa1 = (const float*)d_in[2];
    const float* ba1 = (const float*)d_in[3];
    const float* gla = (const float*)d_in[4];
    const float* bla = (const float*)d_in[5];
    const float* wa2 = (const float*)d_in[6];
    const float* ba2 = (const float*)d_in[7];
    const float* wg1 = (const float*)d_in[8];
    const float* bg1 = (const float*)d_in[9];
    const float* glg = (const float*)d_in[10];
    const float* blg = (const float*)d_in[11];
    const float* wg2 = (const float*)d_in[12];
    const float* bg2 = (const float*)d_in[13];
    const float* gf  = (const float*)d_in[14];
    const float* bf  = (const float*)d_in[15];
    // d_in[16..23] = wq,bq,wk,bk,wv,bv,wo,bo: dead code in reference (skipped)
    const float* wc1 = (const float*)d_in[24];
    const float* bc1 = (const float*)d_in[25];
    const float* wc2 = (const float*)d_in[26];
    const float* bc2 = (const float*)d_in[27];

    float* ws = (float*)d_ws;
    float* aa = ws;                    // 4*256*128 = 131072 floats
    float* cc = ws + 131072;           // 4*256*128

    float* out = (float*)d_out;

    hipLaunchKernelGGL(k_encode, dim3(256), dim3(256), 0, stream,
        tracks, dets, wa1, ba1, gla, bla, wa2, ba2,
        wg1, bg1, glg, blg, wg2, bg2, gf, bf, wc1, aa, cc);
    hipLaunchKernelGGL(k_pairwise, dim3(1024), dim3(256), 0, stream,
        aa, cc, bc1, wc2, bc2, out);
}

// Round 2
// 177.526 us; speedup vs baseline: 1.3455x; 1.3455x over previous
//
#include <hip/hip_runtime.h>

#define EPS 1e-5f

// ===========================================================================
// NEW PATH (5 kernels, K-split GEMMs, needs 20 MB workspace)
// ws layout (float offsets):
//   part   @ 0        : 8 * 2048 * 256 = 4,194,304   (16 MB; k_gemm2 reuses 6 slices)
//   h1T    @ 4194304  : 256 * 2048     =   524,288   (2 MB)   [k][g] transposed
//   greluT @ 4718592  : 128 * 2048     =   262,144   (1 MB)   [k][g] transposed
//   aout   @ 4980736  : 4*256*128      =   131,072
//   cout   @ 5111808  : 4*256*128      =   131,072
// total 5,242,880 floats = 20.97 MB
// ===========================================================================

// GEMM1 partial: part[ksi][g][c] = sum_{k in slice} x[g][k] * wa1[k][c]
// grid 1024 = 128 row-tiles(16 rows) x 8 k-slices(128). No LDS: row operand is
// wave-uniform -> scalar loads; weight load coalesced; 16 independent FMAs.
__global__ __launch_bounds__(256) void k_gemm1(
    const float* __restrict__ tracks, const float* __restrict__ dets,
    const float* __restrict__ wa1, float* __restrict__ part)
{
    const int blk = blockIdx.x;
    const int rt  = blk >> 3;          // 0..127
    const int ksi = blk & 7;
    const int g0  = rt * 16;           // global row (side*1024 + b*256 + n)
    const int side = g0 >> 10, b = (g0 >> 8) & 3, n0 = g0 & 255;
    const float* xb = (side ? dets : tracks) + (size_t)b * (1028 * 256);
    const int k0 = ksi * 128;
    const int c  = threadIdx.x;

    float acc[16];
#pragma unroll
    for (int i = 0; i < 16; ++i) acc[i] = 0.f;

#pragma unroll 2
    for (int f = 0; f < 128; ++f) {
        const float* xr = xb + (size_t)(k0 + f) * 256 + n0;   // wave-uniform
        float4 v0 = *(const float4*)(xr + 0);
        float4 v1 = *(const float4*)(xr + 4);
        float4 v2 = *(const float4*)(xr + 8);
        float4 v3 = *(const float4*)(xr + 12);
        float w = wa1[(size_t)(k0 + f) * 256 + c];            // coalesced
        acc[0]  = fmaf(v0.x, w, acc[0]);  acc[1]  = fmaf(v0.y, w, acc[1]);
        acc[2]  = fmaf(v0.z, w, acc[2]);  acc[3]  = fmaf(v0.w, w, acc[3]);
        acc[4]  = fmaf(v1.x, w, acc[4]);  acc[5]  = fmaf(v1.y, w, acc[5]);
        acc[6]  = fmaf(v1.z, w, acc[6]);  acc[7]  = fmaf(v1.w, w, acc[7]);
        acc[8]  = fmaf(v2.x, w, acc[8]);  acc[9]  = fmaf(v2.y, w, acc[9]);
        acc[10] = fmaf(v2.z, w, acc[10]); acc[11] = fmaf(v2.w, w, acc[11]);
        acc[12] = fmaf(v3.x, w, acc[12]); acc[13] = fmaf(v3.y, w, acc[13]);
        acc[14] = fmaf(v3.z, w, acc[14]); acc[15] = fmaf(v3.w, w, acc[15]);
    }
    float* pb = part + ((size_t)ksi * 2048 + g0) * 256 + c;
#pragma unroll
    for (int i = 0; i < 16; ++i) pb[(size_t)i * 256] = acc[i];
}

// Reduce 8 partials + ba1, LN(256), relu -> h1T[k][g]; geo-MLP LN relu -> greluT
// grid 512 blocks x 4 rows.
__global__ __launch_bounds__(256) void k_reduce1(
    const float* __restrict__ tracks, const float* __restrict__ dets,
    const float* __restrict__ part,
    const float* __restrict__ ba1, const float* __restrict__ gla,
    const float* __restrict__ bla,
    const float* __restrict__ wg1, const float* __restrict__ bg1,
    const float* __restrict__ glg, const float* __restrict__ blg,
    float* __restrict__ h1T, float* __restrict__ greluT)
{
    __shared__ float red[4][4][2];
    __shared__ float geo_s[4][4];
    const int blk = blockIdx.x;
    const int g0 = blk * 4;
    const int side = g0 >> 10, b = (g0 >> 8) & 3, n0 = g0 & 255;
    const float* xb = (side ? dets : tracks) + (size_t)b * (1028 * 256);
    const int tid = threadIdx.x, wave = tid >> 6, lane = tid & 63, c = tid;

    if (tid < 16)
        geo_s[tid >> 2][tid & 3] =
            xb[(size_t)(1024 + (tid & 3)) * 256 + n0 + (tid >> 2)];

    float h[4];
#pragma unroll
    for (int i = 0; i < 4; ++i) {
        float s = ba1[c];
#pragma unroll
        for (int s8 = 0; s8 < 8; ++s8)
            s += part[((size_t)s8 * 2048 + g0 + i) * 256 + c];
        h[i] = s;
    }
#pragma unroll
    for (int i = 0; i < 4; ++i) {
        float s = h[i], s2 = h[i] * h[i];
#pragma unroll
        for (int off = 32; off >= 1; off >>= 1) {
            s  += __shfl_xor(s,  off, 64);
            s2 += __shfl_xor(s2, off, 64);
        }
        if (lane == 0) { red[wave][i][0] = s; red[wave][i][1] = s2; }
    }
    __syncthreads();
    {
        float gv = gla[c], bv = bla[c];
        float o[4];
#pragma unroll
        for (int i = 0; i < 4; ++i) {
            float s  = red[0][i][0] + red[1][i][0] + red[2][i][0] + red[3][i][0];
            float s2 = red[0][i][1] + red[1][i][1] + red[2][i][1] + red[3][i][1];
            float m   = s * (1.f / 256.f);
            float var = s2 * (1.f / 256.f) - m * m;
            o[i] = fmaxf((h[i] - m) * rsqrtf(var + EPS) * gv + bv, 0.f);
        }
        *(float4*)(h1T + (size_t)c * 2048 + g0) =
            make_float4(o[0], o[1], o[2], o[3]);
    }
    __syncthreads();   // red reads done before geo overwrites

    float gh[4];
    if (tid < 128) {
        const int j = tid;
#pragma unroll
        for (int i = 0; i < 4; ++i) {
            float s = bg1[j];
#pragma unroll
            for (int f = 0; f < 4; ++f)
                s = fmaf(geo_s[i][f], wg1[f * 128 + j], s);
            gh[i] = s;
        }
#pragma unroll
        for (int i = 0; i < 4; ++i) {
            float s = gh[i], s2 = gh[i] * gh[i];
#pragma unroll
            for (int off = 32; off >= 1; off >>= 1) {
                s  += __shfl_xor(s,  off, 64);
                s2 += __shfl_xor(s2, off, 64);
            }
            if (lane == 0) { red[wave][i][0] = s; red[wave][i][1] = s2; }
        }
    }
    __syncthreads();
    if (tid < 128) {
        const int j = tid;
        float gv = glg[j], bv = blg[j];
        float o[4];
#pragma unroll
        for (int i = 0; i < 4; ++i) {
            float s  = red[0][i][0] + red[1][i][0];
            float s2 = red[0][i][1] + red[1][i][1];
            float m   = s * (1.f / 128.f);
            float var = s2 * (1.f / 128.f) - m * m;
            o[i] = fmaxf((gh[i] - m) * rsqrtf(var + EPS) * gv + bv, 0.f);
        }
        *(float4*)(greluT + (size_t)j * 2048 + g0) =
            make_float4(o[0], o[1], o[2], o[3]);
    }
}

// GEMM2 partial: part[sl][g][c] = sum_{k in 64-slice} h1ext[g][k] * W[k][c]
// K=384 (h1 256 ++ grelu 128), 6 slices. grid 768 = 128 row-tiles x 6.
__global__ __launch_bounds__(256) void k_gemm2(
    const float* __restrict__ h1T, const float* __restrict__ greluT,
    const float* __restrict__ wa2, const float* __restrict__ wg2,
    float* __restrict__ part)
{
    const int blk = blockIdx.x;
    const int rt = blk / 6, sl = blk - rt * 6;
    const int g0 = rt * 16;
    const int k0 = sl * 64;
    const int c  = threadIdx.x;
    const float* At = (k0 < 256) ? (h1T + (size_t)k0 * 2048)
                                 : (greluT + (size_t)(k0 - 256) * 2048);
    const float* Wb = (k0 < 256) ? (wa2 + (size_t)k0 * 256)
                                 : (wg2 + (size_t)(k0 - 256) * 256);

    float acc[16];
#pragma unroll
    for (int i = 0; i < 16; ++i) acc[i] = 0.f;

#pragma unroll 2
    for (int f = 0; f < 64; ++f) {
        const float* ar = At + (size_t)f * 2048 + g0;         // wave-uniform
        float4 v0 = *(const float4*)(ar + 0);
        float4 v1 = *(const float4*)(ar + 4);
        float4 v2 = *(const float4*)(ar + 8);
        float4 v3 = *(const float4*)(ar + 12);
        float w = Wb[(size_t)f * 256 + c];
        acc[0]  = fmaf(v0.x, w, acc[0]);  acc[1]  = fmaf(v0.y, w, acc[1]);
        acc[2]  = fmaf(v0.z, w, acc[2]);  acc[3]  = fmaf(v0.w, w, acc[3]);
        acc[4]  = fmaf(v1.x, w, acc[4]);  acc[5]  = fmaf(v1.y, w, acc[5]);
        acc[6]  = fmaf(v1.z, w, acc[6]);  acc[7]  = fmaf(v1.w, w, acc[7]);
        acc[8]  = fmaf(v2.x, w, acc[8]);  acc[9]  = fmaf(v2.y, w, acc[9]);
        acc[10] = fmaf(v2.z, w, acc[10]); acc[11] = fmaf(v2.w, w, acc[11]);
        acc[12] = fmaf(v3.x, w, acc[12]); acc[13] = fmaf(v3.y, w, acc[13]);
        acc[14] = fmaf(v3.z, w, acc[14]); acc[15] = fmaf(v3.w, w, acc[15]);
    }
    float* pb = part + ((size_t)sl * 2048 + g0) * 256 + c;
#pragma unroll
    for (int i = 0; i < 16; ++i) pb[(size_t)i * 256] = acc[i];
}

// Reduce 6 partials + ba2+bg2, LN(gf,bf), project with wc1 half -> a/c rows.
// grid 512 blocks x 4 rows.
__global__ __launch_bounds__(256) void k_reduce2(
    const float* __restrict__ part,
    const float* __restrict__ ba2, const float* __restrict__ bg2,
    const float* __restrict__ gf,  const float* __restrict__ bf,
    const float* __restrict__ wc1,
    float* __restrict__ aout, float* __restrict__ cout)
{
    __shared__ float red[4][4][2];
    __shared__ float emb[256 * 4];        // [k][row]
    __shared__ float psum[2][4][128];
    const int blk = blockIdx.x;
    const int g0 = blk * 4;
    const int side = g0 >> 10, b = (g0 >> 8) & 3, nin = g0 & 255;
    const int tid = threadIdx.x, wave = tid >> 6, lane = tid & 63, c = tid;

    float h2[4];
#pragma unroll
    for (int i = 0; i < 4; ++i) {
        float s = ba2[c] + bg2[c];
#pragma unroll
        for (int sl = 0; sl < 6; ++sl)
            s += part[((size_t)sl * 2048 + g0 + i) * 256 + c];
        h2[i] = s;
    }
#pragma unroll
    for (int i = 0; i < 4; ++i) {
        float s = h2[i], s2 = h2[i] * h2[i];
#pragma unroll
        for (int off = 32; off >= 1; off >>= 1) {
            s  += __shfl_xor(s,  off, 64);
            s2 += __shfl_xor(s2, off, 64);
        }
        if (lane == 0) { red[wave][i][0] = s; red[wave][i][1] = s2; }
    }
    __syncthreads();
    {
        float gv = gf[c], bv = bf[c];
        float e[4];
#pragma unroll
        for (int i = 0; i < 4; ++i) {
            float s  = red[0][i][0] + red[1][i][0] + red[2][i][0] + red[3][i][0];
            float s2 = red[0][i][1] + red[1][i][1] + red[2][i][1] + red[3][i][1];
            float m   = s * (1.f / 256.f);
            float var = s2 * (1.f / 256.f) - m * m;
            e[i] = (h2[i] - m) * rsqrtf(var + EPS) * gv + bv;
        }
        *(float4*)(emb + (size_t)c * 4) = make_float4(e[0], e[1], e[2], e[3]);
    }
    __syncthreads();

    const int half = tid >> 7, j = tid & 127;
    const float* wch = wc1 + (size_t)side * (256 * 128);
    float a4[4] = {0.f, 0.f, 0.f, 0.f};
#pragma unroll 4
    for (int k = 0; k < 128; ++k) {
        int kk = half * 128 + k;
        float w = wch[(size_t)kk * 128 + j];                  // coalesced
        float4 ev = *(const float4*)(emb + kk * 4);           // broadcast
        a4[0] = fmaf(ev.x, w, a4[0]); a4[1] = fmaf(ev.y, w, a4[1]);
        a4[2] = fmaf(ev.z, w, a4[2]); a4[3] = fmaf(ev.w, w, a4[3]);
    }
#pragma unroll
    for (int i = 0; i < 4; ++i) psum[half][i][j] = a4[i];
    __syncthreads();

    float* outp = (side ? cout : aout) + ((size_t)b * 256 + nin) * 128;
    for (int idx = tid; idx < 512; idx += 256) {
        int i = idx >> 7, jo = idx & 127;
        outp[(size_t)i * 128 + jo] = psum[0][i][jo] + psum[1][i][jo];
    }
}

// Pairwise: logits[b,n,m] = sum_j relu(a[n,j]+c[m,j]+bc1[j])*wc2[j] + bc2
// float4 LDS, wc2 via uniform scalar loads. grid 1024, 16x16 tile/block.
__global__ __launch_bounds__(256) void k_pairwise(
    const float* __restrict__ a, const float* __restrict__ cmat,
    const float* __restrict__ bc1, const float* __restrict__ wc2,
    const float* __restrict__ bc2, float* __restrict__ out)
{
    __shared__ float4 a_s[16 * 33];
    __shared__ float4 c_s[16 * 33];
    const int blk = blockIdx.x;
    const int b  = blk >> 8;
    const int n0 = ((blk >> 4) & 15) << 4;
    const int m0 = (blk & 15) << 4;
    const int tid = threadIdx.x;

    const float4* a4  = (const float4*)(a    + ((size_t)b * 256 + n0) * 128);
    const float4* c4  = (const float4*)(cmat + ((size_t)b * 256 + m0) * 128);
    const float4* b14 = (const float4*)bc1;
    for (int idx = tid; idx < 512; idx += 256) {
        int r = idx >> 5, q = idx & 31;
        float4 av = a4[r * 32 + q], bv = b14[q];
        a_s[r * 33 + q] = make_float4(av.x + bv.x, av.y + bv.y,
                                      av.z + bv.z, av.w + bv.w);
        c_s[r * 33 + q] = c4[r * 32 + q];
    }
    __syncthreads();

    const int ni = tid >> 4, mi = tid & 15;
    const float4* wp = (const float4*)wc2;
    float acc = bc2[0];
#pragma unroll 8
    for (int q = 0; q < 32; ++q) {
        float4 av = a_s[ni * 33 + q];
        float4 cv = c_s[mi * 33 + q];
        float4 wv = wp[q];                                    // uniform s_load
        acc = fmaf(fmaxf(av.x + cv.x, 0.f), wv.x, acc);
        acc = fmaf(fmaxf(av.y + cv.y, 0.f), wv.y, acc);
        acc = fmaf(fmaxf(av.z + cv.z, 0.f), wv.z, acc);
        acc = fmaf(fmaxf(av.w + cv.w, 0.f), wv.w, acc);
    }
    out[((size_t)b * 256 + n0 + ni) * 256 + m0 + mi] = acc;
}

// ===========================================================================
// FALLBACK PATH (round-1 fused encoder, needs only 1 MB ws) — used iff
// ws_size is too small for the partial-sum pipeline.
// ===========================================================================
#define TILE 8
__global__ __launch_bounds__(256) void k_encode(
    const float* __restrict__ tracks, const float* __restrict__ dets,
    const float* __restrict__ wa1, const float* __restrict__ ba1,
    const float* __restrict__ gla, const float* __restrict__ bla,
    const float* __restrict__ wa2, const float* __restrict__ ba2,
    const float* __restrict__ wg1, const float* __restrict__ bg1,
    const float* __restrict__ glg, const float* __restrict__ blg,
    const float* __restrict__ wg2, const float* __restrict__ bg2,
    const float* __restrict__ gf,  const float* __restrict__ bf,
    const float* __restrict__ wc1,
    float* __restrict__ aout, float* __restrict__ cout)
{
    __shared__ float xs[1024 * TILE];
    __shared__ float red[4][TILE][2];
    __shared__ float geo_s[TILE][4];
    float* h1s   = xs;
    float* grelu = xs + TILE * 256;
    float* emb   = xs + TILE * 384;
    float* psum  = xs + TILE * 640;

    const int blk  = blockIdx.x;
    const int side = blk >> 7;
    const int rem  = blk & 127;
    const int b    = rem >> 5;
    const int n0   = (rem & 31) * TILE;
    const float* x  = side ? dets : tracks;
    const float* xb = x + (size_t)b * (1028 * 256);
    const int tid  = threadIdx.x;
    const int wave = tid >> 6, lane = tid & 63;
    const int c    = tid;
    const int j    = tid & 127;

    for (int idx = tid; idx < 1024 * TILE; idx += 256) {
        int f = idx >> 3, i = idx & 7;
        xs[idx] = xb[f * 256 + n0 + i];
    }
    if (tid < TILE * 4)
        geo_s[tid >> 2][tid & 3] = xb[(1024 + (tid & 3)) * 256 + n0 + (tid >> 2)];
    __syncthreads();

    float acc[TILE];
#pragma unroll
    for (int i = 0; i < TILE; ++i) acc[i] = 0.f;
#pragma unroll 4
    for (int f = 0; f < 1024; ++f) {
        float w = wa1[f * 256 + c];
#pragma unroll
        for (int i = 0; i < TILE; ++i)
            acc[i] = fmaf(xs[f * TILE + i], w, acc[i]);
    }
    { float bav = ba1[c];
#pragma unroll
      for (int i = 0; i < TILE; ++i) acc[i] += bav; }
#pragma unroll
    for (int i = 0; i < TILE; ++i) {
        float s = acc[i], s2 = acc[i] * acc[i];
#pragma unroll
        for (int off = 32; off >= 1; off >>= 1) {
            s += __shfl_xor(s, off, 64); s2 += __shfl_xor(s2, off, 64);
        }
        if (lane == 0) { red[wave][i][0] = s; red[wave][i][1] = s2; }
    }
    __syncthreads();
    { float gv = gla[c], bv = bla[c];
#pragma unroll
      for (int i = 0; i < TILE; ++i) {
        float s  = red[0][i][0] + red[1][i][0] + red[2][i][0] + red[3][i][0];
        float s2 = red[0][i][1] + red[1][i][1] + red[2][i][1] + red[3][i][1];
        float m = s * (1.f/256.f), var = s2 * (1.f/256.f) - m * m;
        h1s[i * 256 + c] = fmaxf((acc[i]-m)*rsqrtf(var+EPS)*gv+bv, 0.f);
      } }
    __syncthreads();

    float ghv[TILE];
    if (tid < 128) {
#pragma unroll
        for (int i = 0; i < TILE; ++i) {
            float s = bg1[j];
#pragma unroll
            for (int f = 0; f < 4; ++f) s = fmaf(geo_s[i][f], wg1[f*128+j], s);
            ghv[i] = s;
        }
#pragma unroll
        for (int i = 0; i < TILE; ++i) {
            float s = ghv[i], s2 = ghv[i]*ghv[i];
#pragma unroll
            for (int off = 32; off >= 1; off >>= 1) {
                s += __shfl_xor(s, off, 64); s2 += __shfl_xor(s2, off, 64);
            }
            if (lane == 0) { red[wave][i][0] = s; red[wave][i][1] = s2; }
        }
    }
    __syncthreads();
    if (tid < 128) {
        float gvj = glg[j], bvj = blg[j];
#pragma unroll
        for (int i = 0; i < TILE; ++i) {
            float s  = red[0][i][0] + red[1][i][0];
            float s2 = red[0][i][1] + red[1][i][1];
            float m = s * (1.f/128.f), var = s2 * (1.f/128.f) - m * m;
            grelu[i*128+j] = fmaxf((ghv[i]-m)*rsqrtf(var+EPS)*gvj+bvj, 0.f);
        }
    }
    __syncthreads();

    float acc2[TILE];
    { float bb = ba2[c] + bg2[c];
#pragma unroll
      for (int i = 0; i < TILE; ++i) acc2[i] = bb; }
#pragma unroll 4
    for (int k = 0; k < 256; ++k) {
        float w = wa2[k * 256 + c];
#pragma unroll
        for (int i = 0; i < TILE; ++i) acc2[i] = fmaf(h1s[i*256+k], w, acc2[i]);
    }
#pragma unroll 4
    for (int k = 0; k < 128; ++k) {
        float w = wg2[k * 256 + c];
#pragma unroll
        for (int i = 0; i < TILE; ++i) acc2[i] = fmaf(grelu[i*128+k], w, acc2[i]);
    }
#pragma unroll
    for (int i = 0; i < TILE; ++i) {
        float s = acc2[i], s2 = acc2[i]*acc2[i];
#pragma unroll
        for (int off = 32; off >= 1; off >>= 1) {
            s += __shfl_xor(s, off, 64); s2 += __shfl_xor(s2, off, 64);
        }
        if (lane == 0) { red[wave][i][0] = s; red[wave][i][1] = s2; }
    }
    __syncthreads();
    { float gfc = gf[c], bfc = bf[c];
#pragma unroll
      for (int i = 0; i < TILE; ++i) {
        float s  = red[0][i][0] + red[1][i][0] + red[2][i][0] + red[3][i][0];
        float s2 = red[0][i][1] + red[1][i][1] + red[2][i][1] + red[3][i][1];
        float m = s * (1.f/256.f), var = s2 * (1.f/256.f) - m * m;
        emb[i*256+c] = (acc2[i]-m)*rsqrtf(var+EPS)*gfc+bfc;
      } }
    __syncthreads();

    const float* wc1h = wc1 + (size_t)side * (256 * 128);
    const int half = tid >> 7;
    float p[TILE];
#pragma unroll
    for (int i = 0; i < TILE; ++i) p[i] = 0.f;
#pragma unroll 4
    for (int k = half * 128; k < half * 128 + 128; ++k) {
        float w = wc1h[k * 128 + j];
#pragma unroll
        for (int i = 0; i < TILE; ++i) p[i] = fmaf(emb[i*256+k], w, p[i]);
    }
#pragma unroll
    for (int i = 0; i < TILE; ++i) psum[(half*TILE+i)*128+j] = p[i];
    __syncthreads();
    float* outp = (side ? cout : aout) + ((size_t)b * 256 + n0) * 128;
    for (int idx = tid; idx < TILE * 128; idx += 256) {
        int i = idx >> 7, jo = idx & 127;
        outp[i*128+jo] = psum[i*128+jo] + psum[(TILE+i)*128+jo];
    }
}

extern "C" void kernel_launch(void* const* d_in, const int* in_sizes, int n_in,
                              void* d_out, int out_size, void* d_ws, size_t ws_size,
                              hipStream_t stream)
{
    const float* tracks = (const float*)d_in[0];
    const float* dets   = (const float*)d_in[1];
    const float* wa1 = (const float*)d_in[2];
    const float* ba1 = (const float*)d_in[3];
    const float* gla = (const float*)d_in[4];
    const float* bla = (const float*)d_in[5];
    const float* wa2 = (const float*)d_in[6];
    const float* ba2 = (const float*)d_in[7];
    const float* wg1 = (const float*)d_in[8];
    const float* bg1 = (const float*)d_in[9];
    const float* glg = (const float*)d_in[10];
    const float* blg = (const float*)d_in[11];
    const float* wg2 = (const float*)d_in[12];
    const float* bg2 = (const float*)d_in[13];
    const float* gf  = (const float*)d_in[14];
    const float* bf  = (const float*)d_in[15];
    // d_in[16..23]: attention weights — dead code in reference.
    const float* wc1 = (const float*)d_in[24];
    const float* bc1 = (const float*)d_in[25];
    const float* wc2 = (const float*)d_in[26];
    const float* bc2 = (const float*)d_in[27];
    float* out = (float*)d_out;
    float* ws  = (float*)d_ws;

    const size_t need = (size_t)5242880 * sizeof(float);   // 20.97 MB
    if (ws_size >= need) {
        float* part   = ws;
        float* h1T    = ws + 4194304;
        float* greluT = ws + 4718592;
        float* aa     = ws + 4980736;
        float* cc     = ws + 5111808;
        hipLaunchKernelGGL(k_gemm1, dim3(1024), dim3(256), 0, stream,
                           tracks, dets, wa1, part);
        hipLaunchKernelGGL(k_reduce1, dim3(512), dim3(256), 0, stream,
                           tracks, dets, part, ba1, gla, bla,
                           wg1, bg1, glg, blg, h1T, greluT);
        hipLaunchKernelGGL(k_gemm2, dim3(768), dim3(256), 0, stream,
                           h1T, greluT, wa2, wg2, part);
        hipLaunchKernelGGL(k_reduce2, dim3(512), dim3(256), 0, stream,
                           part, ba2, bg2, gf, bf, wc1, aa, cc);
        hipLaunchKernelGGL(k_pairwise, dim3(1024), dim3(256), 0, stream,
                           aa, cc, bc1, wc2, bc2, out);
    } else {
        float* aa = ws;
        float* cc = ws + 131072;
        hipLaunchKernelGGL(k_encode, dim3(256), dim3(256), 0, stream,
                           tracks, dets, wa1, ba1, gla, bla, wa2, ba2,
                           wg1, bg1, glg, blg, wg2, bg2, gf, bf, wc1, aa, cc);
        hipLaunchKernelGGL(k_pairwise, dim3(1024), dim3(256), 0, stream,
                           aa, cc, bc1, wc2, bc2, out);
    }
}

// Round 3
// 176.373 us; speedup vs baseline: 1.3543x; 1.0065x over previous
//
#include <hip/hip_runtime.h>

#define EPS 1e-5f

// ===========================================================================
// ws layout (float offsets), ws_size is 256 MiB (observed from harness fill):
//   part  @ 0       : 8 * 2048 * 256 = 4,194,304 (16 MB; gemm2 reuses 6 slices)
//   h1ext @ 4194304 : 2048 * 384    =   786,432 (3 MB)  row-major [g][384]
//   aout  @ 4980736 : 4*256*128     =   131,072
//   cout  @ 5111808 : 4*256*128     =   131,072
// Attention branch of the reference is dead code (attn_out unused) — skipped.
// ===========================================================================

// GEMM1 partial: part[ksi][g][c] = sum_{k in 128-slice} x[g][k] * wa1[k][c]
// grid 1024 = 128 row-tiles(16 rows) x 8 k-slices. x-slice staged transposed
// in LDS (padded stride 20); inner loop = 4 broadcast ds_read_b128 +
// 1 coalesced weight load + 16 independent FMAs.
__global__ __launch_bounds__(256) void k_gemm1(
    const float* __restrict__ tracks, const float* __restrict__ dets,
    const float* __restrict__ wa1, float* __restrict__ part)
{
    __shared__ float xs[128 * 20];
    const int blk = blockIdx.x;
    const int rt  = blk >> 3;
    const int ksi = blk & 7;
    const int g0  = rt * 16;
    const int side = g0 >> 10, b = (g0 >> 8) & 3, n0 = g0 & 255;
    const float* xb = (side ? dets : tracks) + (size_t)b * (1028 * 256);
    const int k0 = ksi * 128;
    const int c  = threadIdx.x;

    // stage: xs[f*20 + r] = x[(k0+f), n0+r]; lanes over r -> 4x64B segments
    for (int idx = threadIdx.x; idx < 2048; idx += 256) {
        int f = idx >> 4, r = idx & 15;
        xs[f * 20 + r] = xb[(size_t)(k0 + f) * 256 + n0 + r];
    }
    __syncthreads();

    float acc[16];
#pragma unroll
    for (int i = 0; i < 16; ++i) acc[i] = 0.f;

#pragma unroll 2
    for (int f = 0; f < 128; ++f) {
        const float4* xr = (const float4*)(xs + f * 20);   // uniform: broadcast
        float4 v0 = xr[0], v1 = xr[1], v2 = xr[2], v3 = xr[3];
        float w = wa1[(size_t)(k0 + f) * 256 + c];         // coalesced
        acc[0]  = fmaf(v0.x, w, acc[0]);  acc[1]  = fmaf(v0.y, w, acc[1]);
        acc[2]  = fmaf(v0.z, w, acc[2]);  acc[3]  = fmaf(v0.w, w, acc[3]);
        acc[4]  = fmaf(v1.x, w, acc[4]);  acc[5]  = fmaf(v1.y, w, acc[5]);
        acc[6]  = fmaf(v1.z, w, acc[6]);  acc[7]  = fmaf(v1.w, w, acc[7]);
        acc[8]  = fmaf(v2.x, w, acc[8]);  acc[9]  = fmaf(v2.y, w, acc[9]);
        acc[10] = fmaf(v2.z, w, acc[10]); acc[11] = fmaf(v2.w, w, acc[11]);
        acc[12] = fmaf(v3.x, w, acc[12]); acc[13] = fmaf(v3.y, w, acc[13]);
        acc[14] = fmaf(v3.z, w, acc[14]); acc[15] = fmaf(v3.w, w, acc[15]);
    }
    float* pb = part + ((size_t)ksi * 2048 + g0) * 256 + c;
#pragma unroll
    for (int i = 0; i < 16; ++i) pb[(size_t)i * 256] = acc[i];   // coalesced
}

// Reduce 8 partials + ba1, LN(256), relu -> h1ext[g][0..255];
// geo MLP + LN(128) + relu -> h1ext[g][256..383].  grid 512 x 4 rows.
__global__ __launch_bounds__(256) void k_reduce1(
    const float* __restrict__ tracks, const float* __restrict__ dets,
    const float* __restrict__ part,
    const float* __restrict__ ba1, const float* __restrict__ gla,
    const float* __restrict__ bla,
    const float* __restrict__ wg1, const float* __restrict__ bg1,
    const float* __restrict__ glg, const float* __restrict__ blg,
    float* __restrict__ h1ext)
{
    __shared__ float red[4][4][2];
    __shared__ float geo_s[4][4];
    const int blk = blockIdx.x;
    const int g0 = blk * 4;
    const int side = g0 >> 10, b = (g0 >> 8) & 3, n0 = g0 & 255;
    const float* xb = (side ? dets : tracks) + (size_t)b * (1028 * 256);
    const int tid = threadIdx.x, wave = tid >> 6, lane = tid & 63, c = tid;

    if (tid < 16)
        geo_s[tid >> 2][tid & 3] =
            xb[(size_t)(1024 + (tid & 3)) * 256 + n0 + (tid >> 2)];

    float h[4];
#pragma unroll
    for (int i = 0; i < 4; ++i) {
        float s = ba1[c];
#pragma unroll
        for (int s8 = 0; s8 < 8; ++s8)
            s += part[((size_t)s8 * 2048 + g0 + i) * 256 + c];
        h[i] = s;
    }
#pragma unroll
    for (int i = 0; i < 4; ++i) {
        float s = h[i], s2 = h[i] * h[i];
#pragma unroll
        for (int off = 32; off >= 1; off >>= 1) {
            s  += __shfl_xor(s,  off, 64);
            s2 += __shfl_xor(s2, off, 64);
        }
        if (lane == 0) { red[wave][i][0] = s; red[wave][i][1] = s2; }
    }
    __syncthreads();
    {
        float gv = gla[c], bv = bla[c];
#pragma unroll
        for (int i = 0; i < 4; ++i) {
            float s  = red[0][i][0] + red[1][i][0] + red[2][i][0] + red[3][i][0];
            float s2 = red[0][i][1] + red[1][i][1] + red[2][i][1] + red[3][i][1];
            float m   = s * (1.f / 256.f);
            float var = s2 * (1.f / 256.f) - m * m;
            h1ext[(size_t)(g0 + i) * 384 + c] =
                fmaxf((h[i] - m) * rsqrtf(var + EPS) * gv + bv, 0.f);
        }
    }
    __syncthreads();   // red reads done before geo phase overwrites

    float gh[4];
    if (tid < 128) {
        const int j = tid;
#pragma unroll
        for (int i = 0; i < 4; ++i) {
            float s = bg1[j];
#pragma unroll
            for (int f = 0; f < 4; ++f)
                s = fmaf(geo_s[i][f], wg1[f * 128 + j], s);
            gh[i] = s;
        }
#pragma unroll
        for (int i = 0; i < 4; ++i) {
            float s = gh[i], s2 = gh[i] * gh[i];
#pragma unroll
            for (int off = 32; off >= 1; off >>= 1) {
                s  += __shfl_xor(s,  off, 64);
                s2 += __shfl_xor(s2, off, 64);
            }
            if (lane == 0) { red[wave][i][0] = s; red[wave][i][1] = s2; }
        }
    }
    __syncthreads();
    if (tid < 128) {
        const int j = tid;
        float gv = glg[j], bv = blg[j];
#pragma unroll
        for (int i = 0; i < 4; ++i) {
            float s  = red[0][i][0] + red[1][i][0];
            float s2 = red[0][i][1] + red[1][i][1];
            float m   = s * (1.f / 128.f);
            float var = s2 * (1.f / 128.f) - m * m;
            h1ext[(size_t)(g0 + i) * 384 + 256 + j] =
                fmaxf((gh[i] - m) * rsqrtf(var + EPS) * gv + bv, 0.f);
        }
    }
}

// GEMM2 partial: part[sl][g][c] = sum_{k in 64-slice} h1ext[g][k] * W[k][c]
// K=384 total, 6 slices. grid 768 = 128 row-tiles x 6 slices.
__global__ __launch_bounds__(256) void k_gemm2(
    const float* __restrict__ h1ext,
    const float* __restrict__ wa2, const float* __restrict__ wg2,
    float* __restrict__ part)
{
    __shared__ float xs[64 * 20];
    const int blk = blockIdx.x;
    const int rt = blk / 6, sl = blk - rt * 6;
    const int g0 = rt * 16;
    const int k0 = sl * 64;
    const int c  = threadIdx.x;
    const float* Wb = (k0 < 256) ? (wa2 + (size_t)k0 * 256)
                                 : (wg2 + (size_t)(k0 - 256) * 256);

    // stage: coalesced global read (lanes over f), LDS write minor-conflicted
    for (int idx = threadIdx.x; idx < 1024; idx += 256) {
        int f = idx & 63, r = idx >> 6;
        xs[f * 20 + r] = h1ext[(size_t)(g0 + r) * 384 + k0 + f];
    }
    __syncthreads();

    float acc[16];
#pragma unroll
    for (int i = 0; i < 16; ++i) acc[i] = 0.f;

#pragma unroll 2
    for (int f = 0; f < 64; ++f) {
        const float4* xr = (const float4*)(xs + f * 20);   // uniform: broadcast
        float4 v0 = xr[0], v1 = xr[1], v2 = xr[2], v3 = xr[3];
        float w = Wb[(size_t)f * 256 + c];
        acc[0]  = fmaf(v0.x, w, acc[0]);  acc[1]  = fmaf(v0.y, w, acc[1]);
        acc[2]  = fmaf(v0.z, w, acc[2]);  acc[3]  = fmaf(v0.w, w, acc[3]);
        acc[4]  = fmaf(v1.x, w, acc[4]);  acc[5]  = fmaf(v1.y, w, acc[5]);
        acc[6]  = fmaf(v1.z, w, acc[6]);  acc[7]  = fmaf(v1.w, w, acc[7]);
        acc[8]  = fmaf(v2.x, w, acc[8]);  acc[9]  = fmaf(v2.y, w, acc[9]);
        acc[10] = fmaf(v2.z, w, acc[10]); acc[11] = fmaf(v2.w, w, acc[11]);
        acc[12] = fmaf(v3.x, w, acc[12]); acc[13] = fmaf(v3.y, w, acc[13]);
        acc[14] = fmaf(v3.z, w, acc[14]); acc[15] = fmaf(v3.w, w, acc[15]);
    }
    float* pb = part + ((size_t)sl * 2048 + g0) * 256 + c;
#pragma unroll
    for (int i = 0; i < 16; ++i) pb[(size_t)i * 256] = acc[i];
}

// Reduce 6 partials + ba2+bg2, LN(gf,bf), project with wc1 half -> a/c rows.
// grid 512 x 4 rows.
__global__ __launch_bounds__(256) void k_reduce2(
    const float* __restrict__ part,
    const float* __restrict__ ba2, const float* __restrict__ bg2,
    const float* __restrict__ gf,  const float* __restrict__ bf,
    const float* __restrict__ wc1,
    float* __restrict__ aout, float* __restrict__ cout)
{
    __shared__ float red[4][4][2];
    __shared__ float emb[256 * 4];        // [k][row]
    __shared__ float psum[2][4][128];
    const int blk = blockIdx.x;
    const int g0 = blk * 4;
    const int side = g0 >> 10, b = (g0 >> 8) & 3, nin = g0 & 255;
    const int tid = threadIdx.x, wave = tid >> 6, lane = tid & 63, c = tid;

    float h2[4];
#pragma unroll
    for (int i = 0; i < 4; ++i) {
        float s = ba2[c] + bg2[c];
#pragma unroll
        for (int sl = 0; sl < 6; ++sl)
            s += part[((size_t)sl * 2048 + g0 + i) * 256 + c];
        h2[i] = s;
    }
#pragma unroll
    for (int i = 0; i < 4; ++i) {
        float s = h2[i], s2 = h2[i] * h2[i];
#pragma unroll
        for (int off = 32; off >= 1; off >>= 1) {
            s  += __shfl_xor(s,  off, 64);
            s2 += __shfl_xor(s2, off, 64);
        }
        if (lane == 0) { red[wave][i][0] = s; red[wave][i][1] = s2; }
    }
    __syncthreads();
    {
        float gv = gf[c], bv = bf[c];
        float e[4];
#pragma unroll
        for (int i = 0; i < 4; ++i) {
            float s  = red[0][i][0] + red[1][i][0] + red[2][i][0] + red[3][i][0];
            float s2 = red[0][i][1] + red[1][i][1] + red[2][i][1] + red[3][i][1];
            float m   = s * (1.f / 256.f);
            float var = s2 * (1.f / 256.f) - m * m;
            e[i] = (h2[i] - m) * rsqrtf(var + EPS) * gv + bv;
        }
        *(float4*)(emb + (size_t)c * 4) = make_float4(e[0], e[1], e[2], e[3]);
    }
    __syncthreads();

    const int half = tid >> 7, j = tid & 127;
    const float* wch = wc1 + (size_t)side * (256 * 128);
    float a4[4] = {0.f, 0.f, 0.f, 0.f};
#pragma unroll 4
    for (int k = 0; k < 128; ++k) {
        int kk = half * 128 + k;
        float w = wch[(size_t)kk * 128 + j];                  // coalesced
        float4 ev = *(const float4*)(emb + kk * 4);           // broadcast
        a4[0] = fmaf(ev.x, w, a4[0]); a4[1] = fmaf(ev.y, w, a4[1]);
        a4[2] = fmaf(ev.z, w, a4[2]); a4[3] = fmaf(ev.w, w, a4[3]);
    }
#pragma unroll
    for (int i = 0; i < 4; ++i) psum[half][i][j] = a4[i];
    __syncthreads();

    float* outp = (side ? cout : aout) + ((size_t)b * 256 + nin) * 128;
    for (int idx = tid; idx < 512; idx += 256) {
        int i = idx >> 7, jo = idx & 127;
        outp[(size_t)i * 128 + jo] = psum[0][i][jo] + psum[1][i][jo];
    }
}

// Pairwise: logits[b,n,m] = sum_j relu(a[n,j]+c[m,j]+bc1[j])*wc2[j] + bc2
// grid 1024, 16x16 tile/block, float4 LDS, wc2 via uniform scalar loads.
__global__ __launch_bounds__(256) void k_pairwise(
    const float* __restrict__ a, const float* __restrict__ cmat,
    const float* __restrict__ bc1, const float* __restrict__ wc2,
    const float* __restrict__ bc2, float* __restrict__ out)
{
    __shared__ float4 a_s[16 * 33];
    __shared__ float4 c_s[16 * 33];
    const int blk = blockIdx.x;
    const int b  = blk >> 8;
    const int n0 = ((blk >> 4) & 15) << 4;
    const int m0 = (blk & 15) << 4;
    const int tid = threadIdx.x;

    const float4* a4  = (const float4*)(a    + ((size_t)b * 256 + n0) * 128);
    const float4* c4  = (const float4*)(cmat + ((size_t)b * 256 + m0) * 128);
    const float4* b14 = (const float4*)bc1;
    for (int idx = tid; idx < 512; idx += 256) {
        int r = idx >> 5, q = idx & 31;
        float4 av = a4[r * 32 + q], bv = b14[q];
        a_s[r * 33 + q] = make_float4(av.x + bv.x, av.y + bv.y,
                                      av.z + bv.z, av.w + bv.w);
        c_s[r * 33 + q] = c4[r * 32 + q];
    }
    __syncthreads();

    const int ni = tid >> 4, mi = tid & 15;
    const float4* wp = (const float4*)wc2;
    float acc = bc2[0];
#pragma unroll 8
    for (int q = 0; q < 32; ++q) {
        float4 av = a_s[ni * 33 + q];
        float4 cv = c_s[mi * 33 + q];
        float4 wv = wp[q];                                    // uniform s_load
        acc = fmaf(fmaxf(av.x + cv.x, 0.f), wv.x, acc);
        acc = fmaf(fmaxf(av.y + cv.y, 0.f), wv.y, acc);
        acc = fmaf(fmaxf(av.z + cv.z, 0.f), wv.z, acc);
        acc = fmaf(fmaxf(av.w + cv.w, 0.f), wv.w, acc);
    }
    out[((size_t)b * 256 + n0 + ni) * 256 + m0 + mi] = acc;
}

extern "C" void kernel_launch(void* const* d_in, const int* in_sizes, int n_in,
                              void* d_out, int out_size, void* d_ws, size_t ws_size,
                              hipStream_t stream)
{
    const float* tracks = (const float*)d_in[0];
    const float* dets   = (const float*)d_in[1];
    const float* wa1 = (const float*)d_in[2];
    const float* ba1 = (const float*)d_in[3];
    const float* gla = (const float*)d_in[4];
    const float* bla = (const float*)d_in[5];
    const float* wa2 = (const float*)d_in[6];
    const float* ba2 = (const float*)d_in[7];
    const float* wg1 = (const float*)d_in[8];
    const float* bg1 = (const float*)d_in[9];
    const float* glg = (const float*)d_in[10];
    const float* blg = (const float*)d_in[11];
    const float* wg2 = (const float*)d_in[12];
    const float* bg2 = (const float*)d_in[13];
    const float* gf  = (const float*)d_in[14];
    const float* bf  = (const float*)d_in[15];
    // d_in[16..23]: attention weights — dead code in reference.
    const float* wc1 = (const float*)d_in[24];
    const float* bc1 = (const float*)d_in[25];
    const float* wc2 = (const float*)d_in[26];
    const float* bc2 = (const float*)d_in[27];
    float* out = (float*)d_out;
    float* ws  = (float*)d_ws;

    float* part  = ws;
    float* h1ext = ws + 4194304;
    float* aa    = ws + 4980736;
    float* cc    = ws + 5111808;

    hipLaunchKernelGGL(k_gemm1, dim3(1024), dim3(256), 0, stream,
                       tracks, dets, wa1, part);
    hipLaunchKernelGGL(k_reduce1, dim3(512), dim3(256), 0, stream,
                       tracks, dets, part, ba1, gla, bla,
                       wg1, bg1, glg, blg, h1ext);
    hipLaunchKernelGGL(k_gemm2, dim3(768), dim3(256), 0, stream,
                       h1ext, wa2, wg2, part);
    hipLaunchKernelGGL(k_reduce2, dim3(512), dim3(256), 0, stream,
                       part, ba2, bg2, gf, bf, wc1, aa, cc);
    hipLaunchKernelGGL(k_pairwise, dim3(1024), dim3(256), 0, stream,
                       aa, cc, bc1, wc2, bc2, out);
}